// Round 1
// baseline (1607.345 us; speedup 1.0000x reference)
//
#include <hip/hip_runtime.h>
#include <math.h>

#define B_ 16
#define N_ 1024
#define KNN 20
#define NPAIR (B_*N_)

// ---------- helpers ----------
__device__ __forceinline__ unsigned fkey(float f) {
  unsigned u = __float_as_uint(f);
  return (u & 0x80000000u) ? ~u : (u | 0x80000000u);
}
__device__ __forceinline__ float fkeyinv(unsigned u) {
  unsigned b = (u & 0x80000000u) ? (u ^ 0x80000000u) : ~u;
  return __uint_as_float(b);
}

// ---------- 1) e2p of raw points ----------
__global__ void k_e2p1(const float* __restrict__ x, float* __restrict__ xp1) {
  int p = blockIdx.x * 256 + threadIdx.x;
  if (p >= NPAIR) return;
  float a0 = x[p*3+0], a1 = x[p*3+1], a2 = x[p*3+2];
  float n = sqrtf(a0*a0 + a1*a1 + a2*a2);
  n = fmaxf(n, 1e-15f);
  float th = tanhf(0.1f * n);
  float sc = th / (0.1f * n);
  float ny = fmaxf(th * 10.0f, 1e-15f);
  float mxn = (1.0f - 4e-3f) / 0.1f;
  if (ny > mxn) sc *= mxn / ny;
  xp1[p*3+0] = sc*a0; xp1[p*3+1] = sc*a1; xp1[p*3+2] = sc*a2;
}

// ---------- 2) knn on raw 3-d points ----------
__global__ void __launch_bounds__(256) k_knn1(const float* __restrict__ x, int* __restrict__ idx1) {
  __shared__ float P[N_*3];
  __shared__ float XX[N_];
  int b = blockIdx.x >> 2;
  int rbase = (blockIdx.x & 3) * 256;
  const float* xb = x + b*N_*3;
  for (int e = threadIdx.x; e < N_*3; e += 256) P[e] = xb[e];
  __syncthreads();
  for (int j = threadIdx.x; j < N_; j += 256) {
    float q0 = P[j*3], q1 = P[j*3+1], q2 = P[j*3+2];
    XX[j] = q0*q0 + q1*q1 + q2*q2;
  }
  __syncthreads();
  int r = rbase + threadIdx.x;
  float q0 = P[r*3], q1 = P[r*3+1], q2 = P[r*3+2];
  float xxq = XX[r];
  float pdl[KNN]; int idl[KNN];
  #pragma unroll
  for (int i = 0; i < KNN; i++) { pdl[i] = -__builtin_inff(); idl[i] = 0; }
  for (int j = 0; j < N_; j++) {
    float dot = q0*P[j*3] + q1*P[j*3+1] + q2*P[j*3+2];
    float d = 2.0f*dot - xxq - XX[j];
    if (d > pdl[KNN-1]) {           // strict: equal pd keeps earlier (lower) index
      pdl[KNN-1] = d; idl[KNN-1] = j;
      #pragma unroll
      for (int i = KNN-1; i > 0; i--) {
        if (pdl[i] > pdl[i-1]) {    // strict: stable among equals
          float tp = pdl[i]; pdl[i] = pdl[i-1]; pdl[i-1] = tp;
          int ti = idl[i]; idl[i] = idl[i-1]; idl[i-1] = ti;
        }
      }
    }
  }
  int* o = idx1 + (b*N_ + r)*KNN;
  #pragma unroll
  for (int i = 0; i < KNN; i++) o[i] = idl[i];
}

// ---------- 3) conv1 fused: mobius feature + 64ch conv + stats + max/min over k ----------
__global__ void __launch_bounds__(256) k_conv1(const float* __restrict__ xp1, const int* __restrict__ idx1,
                        const float* __restrict__ w1, float* __restrict__ hmax1,
                        float* __restrict__ hmin1, double* __restrict__ stats1sh) {
  __shared__ float F[4][KNN][6];
  __shared__ float red[4][64][2];
  int g = threadIdx.x >> 6, lane = threadIdx.x & 63;
  float w[6];
  #pragma unroll
  for (int c = 0; c < 6; c++) w[c] = w1[lane*6 + c];
  float sum = 0.f, sumsq = 0.f;
  int pbase = blockIdx.x * 16;
  for (int it = 0; it < 4; ++it) {
    int p = pbase + it*4 + g;
    if (lane < KNN) {
      int nb = idx1[p*KNN + lane];
      int bb = p >> 10;
      const float* xc = xp1 + p*3;
      const float* ft = xp1 + (bb*N_ + nb)*3;
      float x0 = ft[0], x1 = ft[1], x2v = ft[2];
      float c0 = xc[0], c1 = xc[1], c2 = xc[2];
      float X2 = x0*x0 + x1*x1 + x2v*x2v;
      float Y2 = c0*c0 + c1*c1 + c2*c2;
      float XY = -(x0*c0 + x1*c1 + x2v*c2);
      float den = fmaxf(1.0f + 0.02f*XY + 1e-4f*X2*Y2, 1e-15f);
      float s1 = (1.0f + 0.02f*XY + 0.01f*Y2) / den;
      float s2 = (1.0f - 0.01f*X2) / den;
      F[g][lane][0] = s1*x0 - s2*c0;
      F[g][lane][1] = s1*x1 - s2*c1;
      F[g][lane][2] = s1*x2v - s2*c2;
      F[g][lane][3] = c0; F[g][lane][4] = c1; F[g][lane][5] = c2;
    }
    __syncthreads();
    float mx = -__builtin_inff(), mn = __builtin_inff();
    for (int k = 0; k < KNN; k++) {
      float h = 0.f;
      #pragma unroll
      for (int c = 0; c < 6; c++) h = fmaf(w[c], F[g][k][c], h);
      mx = fmaxf(mx, h); mn = fminf(mn, h);
      sum += h; sumsq += h*h;
    }
    hmax1[p*64 + lane] = mx;
    hmin1[p*64 + lane] = mn;
    __syncthreads();
  }
  red[g][lane][0] = sum; red[g][lane][1] = sumsq;
  __syncthreads();
  if (g == 0) {
    float s  = red[0][lane][0] + red[1][lane][0] + red[2][lane][0] + red[3][lane][0];
    float s2 = red[0][lane][1] + red[1][lane][1] + red[2][lane][1] + red[3][lane][1];
    double* dst = stats1sh + ((size_t)(blockIdx.x & 63)*64 + lane)*2;
    atomicAdd(dst, (double)s);
    atomicAdd(dst + 1, (double)s2);
  }
}

// ---------- BN stat reduce (shadows -> scale/shift) ----------
__global__ void k_bn_reduce(const double* __restrict__ sh, int nsh, int nch, double cnt,
                            const float* __restrict__ g, const float* __restrict__ bb,
                            float* __restrict__ scale, float* __restrict__ shift) {
  int o = blockIdx.x * blockDim.x + threadIdx.x;
  if (o >= nch) return;
  double s = 0.0, s2 = 0.0;
  for (int i = 0; i < nsh; i++) {
    s  += sh[((size_t)i*nch + o)*2];
    s2 += sh[((size_t)i*nch + o)*2 + 1];
  }
  double m = s / cnt;
  double v = s2 / cnt - m*m;
  float a = g[o] / sqrtf((float)v + 1e-5f);
  scale[o] = a;
  shift[o] = bb[o] - a * (float)m;
}

// ---------- 5) BN1 apply + relu (+max already folded) + e2p of x1 ----------
__global__ void __launch_bounds__(256) k_bn1_apply(const float* __restrict__ hmax1, const float* __restrict__ hmin1,
                            const float* __restrict__ scale1, const float* __restrict__ shift1,
                            float* __restrict__ feat3, float* __restrict__ xp2) {
  int p = blockIdx.x*4 + (threadIdx.x >> 6);
  int c = threadIdx.x & 63;
  float a = scale1[c], t = shift1[c];
  float h = (a >= 0.f) ? hmax1[p*64 + c] : hmin1[p*64 + c];
  float x1 = fmaxf(fmaf(a, h, t), 0.f);
  feat3[p*256 + c] = x1;
  float n2 = x1*x1;
  #pragma unroll
  for (int off = 32; off > 0; off >>= 1) n2 += __shfl_xor(n2, off);
  float n = fmaxf(sqrtf(n2), 1e-15f);
  float th = tanhf(0.1f * n);
  float sc = th / (0.1f * n);
  float ny = fmaxf(th * 10.0f, 1e-15f);
  float mxn = (1.0f - 4e-3f) / 0.1f;
  if (ny > mxn) sc *= mxn / ny;
  xp2[p*64 + c] = sc * x1;
}

// ---------- 6) knn on 64-d x1 (4-way candidate split) ----------
__global__ void __launch_bounds__(128) k_knn2(const float* __restrict__ feat3,
        float* __restrict__ pdpart, int* __restrict__ idxpart) {
  __shared__ float Ct[128][64];
  __shared__ float XXs[128];
  int blk = blockIdx.x;
  int b = blk >> 5, rc = (blk >> 2) & 7, cc = blk & 3;
  int row = rc*128 + threadIdx.x;
  int p = b*N_ + row;
  float4 q[16];
  const float4* qv = (const float4*)(feat3 + (size_t)p*256);
  #pragma unroll
  for (int i = 0; i < 16; i++) q[i] = qv[i];
  float xxq = 0.f;
  #pragma unroll
  for (int i = 0; i < 16; i++) xxq += q[i].x*q[i].x + q[i].y*q[i].y + q[i].z*q[i].z + q[i].w*q[i].w;
  float pdl[KNN]; int idl[KNN];
  #pragma unroll
  for (int i = 0; i < KNN; i++) { pdl[i] = -__builtin_inff(); idl[i] = 0; }
  for (int sub = 0; sub < 2; ++sub) {
    int cbase = cc*256 + sub*128;
    __syncthreads();
    for (int e = threadIdx.x; e < 128*16; e += 128) {
      int rr = e >> 4, c4 = e & 15;
      ((float4*)Ct[rr])[c4] = *((const float4*)(feat3 + (size_t)(b*N_ + cbase + rr)*256) + c4);
    }
    __syncthreads();
    {
      float s = 0.f;
      const float4* cr = (const float4*)Ct[threadIdx.x];
      #pragma unroll
      for (int i = 0; i < 16; i++) { float4 v = cr[i]; s += v.x*v.x + v.y*v.y + v.z*v.z + v.w*v.w; }
      XXs[threadIdx.x] = s;
    }
    __syncthreads();
    for (int j = 0; j < 128; j++) {
      const float4* cj = (const float4*)Ct[j];
      float dot = 0.f;
      #pragma unroll
      for (int i = 0; i < 16; i++) {
        float4 v = cj[i];
        dot = fmaf(q[i].x, v.x, dot); dot = fmaf(q[i].y, v.y, dot);
        dot = fmaf(q[i].z, v.z, dot); dot = fmaf(q[i].w, v.w, dot);
      }
      float d = 2.0f*dot - xxq - XXs[j];
      if (d > pdl[KNN-1]) {
        pdl[KNN-1] = d; idl[KNN-1] = cbase + j;
        #pragma unroll
        for (int i = KNN-1; i > 0; i--) {
          if (pdl[i] > pdl[i-1]) {
            float tp = pdl[i]; pdl[i] = pdl[i-1]; pdl[i-1] = tp;
            int ti = idl[i]; idl[i] = idl[i-1]; idl[i-1] = ti;
          }
        }
      }
    }
  }
  float* pe = pdpart + (size_t)p*80 + cc*20;
  int* ie = idxpart + (size_t)p*80 + cc*20;
  #pragma unroll
  for (int i = 0; i < KNN; i++) { pe[i] = pdl[i]; ie[i] = idl[i]; }
}

// ---------- 7) merge 4 sorted top-20 chunks ----------
__global__ void k_knn2_merge(const float* __restrict__ pdpart, const int* __restrict__ idxpart,
                             int* __restrict__ idx2) {
  int p = blockIdx.x*256 + threadIdx.x;
  if (p >= NPAIR) return;
  const float* pe = pdpart + (size_t)p*80;
  const int* ie = idxpart + (size_t)p*80;
  int pos0 = 0, pos1 = 0, pos2 = 0, pos3 = 0;
  int* outp = idx2 + p*KNN;
  for (int t = 0; t < KNN; t++) {
    float best = -__builtin_inff(); int bi = 0x7FFFFFFF; int bc = 0;
    if (pos0 < KNN) { float pv = pe[pos0];      int iv = ie[pos0];      if (pv > best || (pv == best && iv < bi)) { best = pv; bi = iv; bc = 0; } }
    if (pos1 < KNN) { float pv = pe[20 + pos1]; int iv = ie[20 + pos1]; if (pv > best || (pv == best && iv < bi)) { best = pv; bi = iv; bc = 1; } }
    if (pos2 < KNN) { float pv = pe[40 + pos2]; int iv = ie[40 + pos2]; if (pv > best || (pv == best && iv < bi)) { best = pv; bi = iv; bc = 2; } }
    if (pos3 < KNN) { float pv = pe[60 + pos3]; int iv = ie[60 + pos3]; if (pv > best || (pv == best && iv < bi)) { best = pv; bi = iv; bc = 3; } }
    outp[t] = bi;
    if (bc == 0) pos0++; else if (bc == 1) pos1++; else if (bc == 2) pos2++; else pos3++;
  }
}

// ---------- 8) weight transposes ----------
__global__ void k_transpose(const float* __restrict__ w2, const float* __restrict__ w3,
                            float* __restrict__ wt2, float* __restrict__ wt3) {
  int i = blockIdx.x*256 + threadIdx.x;
  if (i < 192*128) { int o = i/128, c = i%128; wt2[c*192 + o] = w2[i]; }
  if (i < 1024*256) { int o = i/256, c = i%256; wt3[c*1024 + o] = w3[i]; }
}

// ---------- 9) conv2 fused: on-the-fly mobius A-tile + GEMM + stats + max/min over k ----------
__global__ void __launch_bounds__(256) k_conv2(const float* __restrict__ xp2,
    const int* __restrict__ idx2, const float* __restrict__ wt2,
    float* __restrict__ hmax2, float* __restrict__ hmin2, double* __restrict__ stats2sh) {
  __shared__ __align__(16) float A[80*132];
  __shared__ __align__(16) float xcs[256];
  __shared__ float s1s[80], s2s[80];
  __shared__ int nbr[80];
  int tid = threadIdx.x;
  int ty = tid >> 4, tx = tid & 15;
  int p0 = blockIdx.x * 4;
  int b = p0 >> 10;
  {
    int g = tid >> 6, c = tid & 63;
    xcs[tid] = xp2[(size_t)(p0 + g)*64 + c];
  }
  if (tid < 80) nbr[tid] = idx2[p0*KNN + tid];
  __syncthreads();
  // phase1: A[r][0:64] = neighbor feat, A[r][64:128] = xc
  for (int e = tid; e < 80*32; e += 256) {
    int r = e >> 5, qq = e & 31;
    if (qq < 16) {
      float4 v = *((const float4*)(xp2 + (size_t)(b*N_ + nbr[r])*64) + qq);
      *((float4*)(A + r*132) + qq) = v;
    } else {
      int g = r / 20;
      *((float4*)(A + r*132 + 64) + (qq - 16)) = *((const float4*)(xcs + g*64) + (qq - 16));
    }
  }
  __syncthreads();
  // phase2: per-row mobius scalars
  if (tid < 80) {
    const float* Ar = A + tid*132;
    float X2 = 0.f, XY = 0.f, Y2 = 0.f;
    for (int c2 = 0; c2 < 64; c2++) {
      float f = Ar[c2], xcv = Ar[64 + c2];
      X2 = fmaf(f, f, X2); XY = fmaf(-f, xcv, XY); Y2 = fmaf(xcv, xcv, Y2);
    }
    float den = fmaxf(1.0f + 0.02f*XY + 1e-4f*X2*Y2, 1e-15f);
    s1s[tid] = (1.0f + 0.02f*XY + 0.01f*Y2) / den;
    s2s[tid] = (1.0f - 0.01f*X2) / den;
  }
  __syncthreads();
  // phase3: A[r][0:64] = s1*feat - s2*xc
  for (int e = tid; e < 80*16; e += 256) {
    int r = e >> 4, qq = e & 15;
    float4 f = *((float4*)(A + r*132) + qq);
    float4 c4v = *((const float4*)(A + r*132 + 64) + qq);
    float s1 = s1s[r], s2 = s2s[r];
    f.x = s1*f.x - s2*c4v.x; f.y = s1*f.y - s2*c4v.y;
    f.z = s1*f.z - s2*c4v.z; f.w = s1*f.w - s2*c4v.w;
    *((float4*)(A + r*132) + qq) = f;
  }
  __syncthreads();
  // GEMM: 80x192, K=128
  float acc[5][12];
  #pragma unroll
  for (int i = 0; i < 5; i++)
    #pragma unroll
    for (int j = 0; j < 12; j++) acc[i][j] = 0.f;
  const float4* wtv = (const float4*)wt2;
  for (int kc = 0; kc < 128; kc++) {
    float4 w0 = wtv[kc*48 + tx];
    float4 w1 = wtv[kc*48 + 16 + tx];
    float4 w2 = wtv[kc*48 + 32 + tx];
    float wv[12] = {w0.x,w0.y,w0.z,w0.w, w1.x,w1.y,w1.z,w1.w, w2.x,w2.y,w2.z,w2.w};
    float ar[5];
    #pragma unroll
    for (int i = 0; i < 5; i++) ar[i] = A[(ty + 16*i)*132 + kc];
    #pragma unroll
    for (int i = 0; i < 5; i++) {
      #pragma unroll
      for (int j = 0; j < 12; j++) acc[i][j] = fmaf(ar[i], wv[j], acc[i][j]);
    }
  }
  __syncthreads();
  // stats: per-channel sum/sumsq -> shadow atomics
  float* redbuf = A;   // reuse (needs 256*25 = 6400 floats)
  #pragma unroll
  for (int cc2 = 0; cc2 < 12; cc2++) {
    float s = 0.f, s2 = 0.f;
    #pragma unroll
    for (int i = 0; i < 5; i++) { float h = acc[i][cc2]; s += h; s2 += h*h; }
    redbuf[tid*25 + cc2*2] = s; redbuf[tid*25 + cc2*2 + 1] = s2;
  }
  __syncthreads();
  if (ty == 0) {
    for (int cc2 = 0; cc2 < 12; cc2++) {
      float s = 0.f, s2 = 0.f;
      for (int yy = 0; yy < 16; yy++) {
        s  += redbuf[(yy*16 + tx)*25 + cc2*2];
        s2 += redbuf[(yy*16 + tx)*25 + cc2*2 + 1];
      }
      int o = (cc2 >> 2)*64 + 4*tx + (cc2 & 3);
      double* dst = stats2sh + ((size_t)(blockIdx.x & 63)*192 + o)*2;
      atomicAdd(dst, (double)s); atomicAdd(dst + 1, (double)s2);
    }
  }
  // max/min over k per (pair, channel)
  float* mmb = A;
  #pragma unroll
  for (int cc2 = 0; cc2 < 12; cc2++) {
    __syncthreads();
    #pragma unroll
    for (int i = 0; i < 5; i++) mmb[(ty + 16*i)*16 + tx] = acc[i][cc2];
    __syncthreads();
    if (tid < 64) {
      int g = tid >> 4, xx2 = tid & 15;
      float mx = -__builtin_inff(), mn = __builtin_inff();
      for (int kk = 0; kk < KNN; kk++) {
        float h = mmb[(g*20 + kk)*16 + xx2];
        mx = fmaxf(mx, h); mn = fminf(mn, h);
      }
      int o = (cc2 >> 2)*64 + 4*xx2 + (cc2 & 3);
      hmax2[(size_t)(p0 + g)*192 + o] = mx;
      hmin2[(size_t)(p0 + g)*192 + o] = mn;
    }
  }
}

// ---------- 10) BN2 apply ----------
__global__ void k_bn2_apply(const float* __restrict__ hmax2, const float* __restrict__ hmin2,
                            const float* __restrict__ scale2, const float* __restrict__ shift2,
                            float* __restrict__ feat3) {
  int e = blockIdx.x*256 + threadIdx.x;
  if (e >= NPAIR*192) return;
  int p = e / 192, o = e - p*192;
  float a = scale2[o], t = shift2[o];
  float h = (a >= 0.f) ? hmax2[e] : hmin2[e];
  feat3[(size_t)p*256 + 64 + o] = fmaxf(fmaf(a, h, t), 0.f);
}

// ---------- 11) conv3 GEMM + stats + max/min over n ----------
__global__ void __launch_bounds__(256) k_conv3(const float* __restrict__ feat3,
   const float* __restrict__ wt3, double* __restrict__ stats3,
   unsigned* __restrict__ hmax3u, unsigned* __restrict__ hmin3u) {
  __shared__ __align__(16) float A[64*68];
  __shared__ float buf[256*16];
  int tid = threadIdx.x, ty = tid >> 4, tx = tid & 15;
  int mt = blockIdx.x >> 2, cb = blockIdx.x & 3;
  int rowbase = mt*64;
  int b = rowbase >> 10;
  float acc[4][16];
  #pragma unroll
  for (int i = 0; i < 4; i++)
    #pragma unroll
    for (int j = 0; j < 16; j++) acc[i][j] = 0.f;
  for (int ch = 0; ch < 4; ch++) {
    int kb = ch*64;
    __syncthreads();
    for (int e = tid; e < 64*16; e += 256) {
      int rr = e >> 4, c4 = e & 15;
      *((float4*)(A + rr*68) + c4) = *((const float4*)(feat3 + (size_t)(rowbase + rr)*256 + kb) + c4);
    }
    __syncthreads();
    for (int kc = 0; kc < 64; kc++) {
      int kglob = kb + kc;
      float4 w[4];
      #pragma unroll
      for (int j = 0; j < 4; j++)
        w[j] = *((const float4*)(wt3 + (size_t)kglob*1024 + cb*256 + j*64 + 4*tx));
      float a[4];
      #pragma unroll
      for (int i = 0; i < 4; i++) a[i] = A[(ty + 16*i)*68 + kc];
      #pragma unroll
      for (int i = 0; i < 4; i++) {
        #pragma unroll
        for (int j = 0; j < 4; j++) {
          acc[i][j*4+0] = fmaf(a[i], w[j].x, acc[i][j*4+0]);
          acc[i][j*4+1] = fmaf(a[i], w[j].y, acc[i][j*4+1]);
          acc[i][j*4+2] = fmaf(a[i], w[j].z, acc[i][j*4+2]);
          acc[i][j*4+3] = fmaf(a[i], w[j].w, acc[i][j*4+3]);
        }
      }
    }
  }
  #pragma unroll
  for (int j = 0; j < 4; j++) {
    __syncthreads();
    #pragma unroll
    for (int q = 0; q < 4; q++) {
      float s = 0.f, s2 = 0.f, mx = -__builtin_inff(), mn = __builtin_inff();
      #pragma unroll
      for (int i = 0; i < 4; i++) {
        float h = acc[i][j*4+q];
        s += h; s2 += h*h; mx = fmaxf(mx, h); mn = fminf(mn, h);
      }
      float* bp = buf + tid*16 + q*4;
      bp[0] = s; bp[1] = s2; bp[2] = mx; bp[3] = mn;
    }
    __syncthreads();
    if (ty == 0) {
      #pragma unroll
      for (int q = 0; q < 4; q++) {
        float s = 0.f, s2 = 0.f, mx = -__builtin_inff(), mn = __builtin_inff();
        for (int yy = 0; yy < 16; yy++) {
          const float* bp = buf + (yy*16 + tx)*16 + q*4;
          s += bp[0]; s2 += bp[1]; mx = fmaxf(mx, bp[2]); mn = fminf(mn, bp[3]);
        }
        int o = cb*256 + j*64 + 4*tx + q;
        atomicAdd(stats3 + (size_t)o*2, (double)s);
        atomicAdd(stats3 + (size_t)o*2 + 1, (double)s2);
        atomicMax(hmax3u + b*1024 + o, fkey(mx));
        atomicMin(hmin3u + b*1024 + o, fkey(mn));
      }
    }
  }
}

// ---------- 12) head: BN3-apply+relu(+max folded) -> fc1+LN+relu -> fc2+LN+relu -> out+log_softmax ----------
__device__ float blk_reduce(float v, float* red, int tid) {
  red[tid] = v; __syncthreads();
  for (int st = 128; st > 0; st >>= 1) {
    if (tid < st) red[tid] += red[tid + st];
    __syncthreads();
  }
  float r = red[0]; __syncthreads();
  return r;
}

__global__ void __launch_bounds__(256) k_head(const unsigned* __restrict__ hmax3u, const unsigned* __restrict__ hmin3u,
    const float* __restrict__ scale3, const float* __restrict__ shift3,
    const float* __restrict__ fc1w, const float* __restrict__ fc1b,
    const float* __restrict__ ln1g, const float* __restrict__ ln1b,
    const float* __restrict__ fc2w, const float* __restrict__ fc2b,
    const float* __restrict__ ln2g, const float* __restrict__ ln2b,
    const float* __restrict__ outw, const float* __restrict__ outb,
    float* __restrict__ out) {
  __shared__ __align__(16) float V[1024];
  __shared__ __align__(16) float H1[512];
  __shared__ __align__(16) float H2[256];
  __shared__ float red[256];
  int b = blockIdx.x, tid = threadIdx.x;
  for (int o = tid; o < 1024; o += 256) {
    float a = scale3[o];
    unsigned u = (a >= 0.f) ? hmax3u[b*1024 + o] : hmin3u[b*1024 + o];
    float h = fkeyinv(u);
    V[o] = fmaxf(fmaf(a, h, shift3[o]), 0.f);
  }
  __syncthreads();
  float h1v[2];
  #pragma unroll
  for (int ii = 0; ii < 2; ii++) {
    int o = tid + ii*256;
    const float4* wr = (const float4*)(fc1w + (size_t)o*1024);
    float s = 0.f;
    for (int c4 = 0; c4 < 256; c4++) {
      float4 w = wr[c4]; float4 vv = ((const float4*)V)[c4];
      s = fmaf(w.x, vv.x, s); s = fmaf(w.y, vv.y, s);
      s = fmaf(w.z, vv.z, s); s = fmaf(w.w, vv.w, s);
    }
    h1v[ii] = s + fc1b[o];
  }
  float s = h1v[0] + h1v[1];
  float s2 = h1v[0]*h1v[0] + h1v[1]*h1v[1];
  s = blk_reduce(s, red, tid);
  s2 = blk_reduce(s2, red, tid);
  float m = s / 512.f;
  float var = s2 / 512.f - m*m;
  float inv = 1.0f / sqrtf(var + 1e-5f);
  #pragma unroll
  for (int ii = 0; ii < 2; ii++) {
    int o = tid + ii*256;
    H1[o] = fmaxf((h1v[ii] - m)*inv*ln1g[o] + ln1b[o], 0.f);
  }
  __syncthreads();
  float h2v;
  {
    const float4* wr = (const float4*)(fc2w + (size_t)tid*512);
    float t = 0.f;
    for (int c4 = 0; c4 < 128; c4++) {
      float4 w = wr[c4]; float4 vv = ((const float4*)H1)[c4];
      t = fmaf(w.x, vv.x, t); t = fmaf(w.y, vv.y, t);
      t = fmaf(w.z, vv.z, t); t = fmaf(w.w, vv.w, t);
    }
    h2v = t + fc2b[tid];
  }
  float ss = blk_reduce(h2v, red, tid);
  float ss2 = blk_reduce(h2v*h2v, red, tid);
  float m2 = ss / 256.f;
  float var2 = ss2 / 256.f - m2*m2;
  float inv2 = 1.0f / sqrtf(var2 + 1e-5f);
  H2[tid] = fmaxf((h2v - m2)*inv2*ln2g[tid] + ln2b[tid], 0.f);
  __syncthreads();
  if (tid < 40) {
    const float4* wr = (const float4*)(outw + (size_t)tid*256);
    float t = 0.f;
    for (int c4 = 0; c4 < 64; c4++) {
      float4 w = wr[c4]; float4 vv = ((const float4*)H2)[c4];
      t = fmaf(w.x, vv.x, t); t = fmaf(w.y, vv.y, t);
      t = fmaf(w.z, vv.z, t); t = fmaf(w.w, vv.w, t);
    }
    red[tid] = t + outb[tid];
  }
  __syncthreads();
  if (tid == 0) {
    float mx = -__builtin_inff();
    for (int i2 = 0; i2 < 40; i2++) mx = fmaxf(mx, red[i2]);
    float se = 0.f;
    for (int i2 = 0; i2 < 40; i2++) se += expf(red[i2] - mx);
    float lse = mx + logf(se);
    for (int i2 = 0; i2 < 40; i2++) out[b*40 + i2] = red[i2] - lse;
  }
}

extern "C" void kernel_launch(void* const* d_in, const int* in_sizes, int n_in,
                              void* d_out, int out_size, void* d_ws, size_t ws_size,
                              hipStream_t stream) {
  (void)in_sizes; (void)n_in; (void)out_size; (void)ws_size;
  const float* x    = (const float*)d_in[0];
  const float* w1   = (const float*)d_in[1];
  const float* bn1g = (const float*)d_in[2];
  const float* bn1b = (const float*)d_in[3];
  const float* w2   = (const float*)d_in[4];
  const float* bn2g = (const float*)d_in[5];
  const float* bn2b = (const float*)d_in[6];
  const float* w3   = (const float*)d_in[7];
  const float* bn3g = (const float*)d_in[8];
  const float* bn3b = (const float*)d_in[9];
  const float* fc1w = (const float*)d_in[10];
  const float* fc1b = (const float*)d_in[11];
  const float* ln1g = (const float*)d_in[12];
  const float* ln1b = (const float*)d_in[13];
  const float* fc2w = (const float*)d_in[14];
  const float* fc2b = (const float*)d_in[15];
  const float* ln2g = (const float*)d_in[16];
  const float* ln2b = (const float*)d_in[17];
  const float* outw = (const float*)d_in[18];
  const float* outb = (const float*)d_in[19];
  float* out = (float*)d_out;

  float* ws = (float*)d_ws;
  size_t off = 0;
  float* xp1   = ws + off; off += 49152;
  int*   idx1  = (int*)(ws + off); off += 327680;
  float* hmax1 = ws + off; off += 1048576;
  float* hmin1 = ws + off; off += 1048576;
  float* feat3 = ws + off; off += 4194304;
  float* xp2   = ws + off; off += 1048576;
  float* hmax2 = ws + off; off += 3145728;   // also pdpart (earlier in pipeline)
  float* hmin2 = ws + off; off += 3145728;   // also idxpart
  int*   idx2  = (int*)(ws + off); off += 327680;
  float* wt2   = ws + off; off += 24576;
  float* wt3   = ws + off; off += 262144;
  float* scale1 = ws + off; off += 64;
  float* shift1 = ws + off; off += 64;
  float* scale2 = ws + off; off += 192;
  float* shift2 = ws + off; off += 192;
  float* scale3 = ws + off; off += 1024;
  float* shift3 = ws + off; off += 1024;
  double* stats1sh = (double*)(ws + off);      // 64*64*2 doubles
  double* stats2sh = stats1sh + 64*64*2;       // 64*192*2 doubles
  double* stats3   = stats2sh + 64*192*2;      // 1024*2 doubles
  unsigned* hmax3u = (unsigned*)(stats3 + 1024*2);  // 16384 u32
  unsigned* hmin3u = hmax3u + 16384;                // 16384 u32
  float* pdpart = hmax2;
  int*   idxpart = (int*)hmin2;

  size_t zero_bytes = (size_t)(64*64*2 + 64*192*2 + 1024*2)*8 + (size_t)16384*4;
  hipMemsetAsync(stats1sh, 0, zero_bytes, stream);
  hipMemsetAsync(hmin3u, 0xFF, (size_t)16384*4, stream);

  k_e2p1<<<64, 256, 0, stream>>>(x, xp1);
  k_knn1<<<64, 256, 0, stream>>>(x, idx1);
  k_transpose<<<1024, 256, 0, stream>>>(w2, w3, wt2, wt3);
  k_conv1<<<1024, 256, 0, stream>>>(xp1, idx1, w1, hmax1, hmin1, stats1sh);
  k_bn_reduce<<<1, 64, 0, stream>>>(stats1sh, 64, 64, 327680.0, bn1g, bn1b, scale1, shift1);
  k_bn1_apply<<<4096, 256, 0, stream>>>(hmax1, hmin1, scale1, shift1, feat3, xp2);
  k_knn2<<<512, 128, 0, stream>>>(feat3, pdpart, idxpart);
  k_knn2_merge<<<64, 256, 0, stream>>>(pdpart, idxpart, idx2);
  k_conv2<<<4096, 256, 0, stream>>>(xp2, idx2, wt2, hmax2, hmin2, stats2sh);
  k_bn_reduce<<<1, 192, 0, stream>>>(stats2sh, 64, 192, 327680.0, bn2g, bn2b, scale2, shift2);
  k_bn2_apply<<<12288, 256, 0, stream>>>(hmax2, hmin2, scale2, shift2, feat3);
  k_conv3<<<1024, 256, 0, stream>>>(feat3, wt3, stats3, hmax3u, hmin3u);
  k_bn_reduce<<<4, 256, 0, stream>>>(stats3, 1, 1024, 16384.0, bn3g, bn3b, scale3, shift3);
  k_head<<<16, 256, 0, stream>>>(hmax3u, hmin3u, scale3, shift3,
                                 fc1w, fc1b, ln1g, ln1b,
                                 fc2w, fc2b, ln2g, ln2b,
                                 outw, outb, out);
}

// Round 2
// 1075.179 us; speedup vs baseline: 1.4950x; 1.4950x over previous
//
#include <hip/hip_runtime.h>
#include <math.h>

#define B_ 16
#define N_ 1024
#define KNN 20
#define NPAIR (B_*N_)

// ---------- helpers ----------
__device__ __forceinline__ unsigned fkey(float f) {
  unsigned u = __float_as_uint(f);
  return (u & 0x80000000u) ? ~u : (u | 0x80000000u);
}
__device__ __forceinline__ float fkeyinv(unsigned u) {
  unsigned b = (u & 0x80000000u) ? (u ^ 0x80000000u) : ~u;
  return __uint_as_float(b);
}

// Branchless (cndmask-chain) insertion into a descending sorted top-20.
// Strict compare keeps earlier (lower-index) entries ahead on ties.
__device__ __forceinline__ void topk_insert(float (&pdl)[KNN], int (&idl)[KNN], float d, int j) {
  pdl[KNN-1] = d; idl[KNN-1] = j;
  #pragma unroll
  for (int i = KNN-1; i > 0; i--) {
    float a = pdl[i-1], bv = pdl[i];
    int ai = idl[i-1], bi = idl[i];
    bool sw = bv > a;
    pdl[i-1] = sw ? bv : a;   pdl[i] = sw ? a  : bv;
    idl[i-1] = sw ? bi : ai;  idl[i] = sw ? ai : bi;
  }
}

// ---------- 1) e2p of raw points ----------
__global__ void k_e2p1(const float* __restrict__ x, float* __restrict__ xp1) {
  int p = blockIdx.x * 256 + threadIdx.x;
  if (p >= NPAIR) return;
  float a0 = x[p*3+0], a1 = x[p*3+1], a2 = x[p*3+2];
  float n = sqrtf(a0*a0 + a1*a1 + a2*a2);
  n = fmaxf(n, 1e-15f);
  float th = tanhf(0.1f * n);
  float sc = th / (0.1f * n);
  float ny = fmaxf(th * 10.0f, 1e-15f);
  float mxn = (1.0f - 4e-3f) / 0.1f;
  if (ny > mxn) sc *= mxn / ny;
  xp1[p*3+0] = sc*a0; xp1[p*3+1] = sc*a1; xp1[p*3+2] = sc*a2;
}

// ---------- 2) knn on raw 3-d points: 4-way candidate split ----------
// grid: b(16) x rowchunk(4) x colchunk(4) = 256 blocks, 256 thr
__global__ void __launch_bounds__(256) k_knn1_part(const float* __restrict__ x,
        float* __restrict__ pdpart, int* __restrict__ idxpart) {
  __shared__ float P[N_*3];
  __shared__ float XX[N_];
  int blk = blockIdx.x;
  int b = blk >> 4, rc = (blk >> 2) & 3, cc = blk & 3;
  const float* xb = x + b*N_*3;
  for (int e = threadIdx.x; e < N_*3; e += 256) P[e] = xb[e];
  __syncthreads();
  for (int j = threadIdx.x; j < N_; j += 256) {
    float q0 = P[j*3], q1 = P[j*3+1], q2 = P[j*3+2];
    XX[j] = q0*q0 + q1*q1 + q2*q2;
  }
  __syncthreads();
  int r = rc*256 + threadIdx.x;
  float q0 = P[r*3], q1 = P[r*3+1], q2 = P[r*3+2];
  float xxq = XX[r];
  float pdl[KNN]; int idl[KNN];
  #pragma unroll
  for (int i = 0; i < KNN; i++) { pdl[i] = -__builtin_inff(); idl[i] = 0; }
  int cbase = cc*256;
  for (int jj = 0; jj < 256; jj++) {
    int j = cbase + jj;
    float dot = q0*P[j*3] + q1*P[j*3+1] + q2*P[j*3+2];
    float d = 2.0f*dot - xxq - XX[j];
    if (d > pdl[KNN-1]) topk_insert(pdl, idl, d, j);
  }
  int p = b*N_ + r;
  float* pe = pdpart + (size_t)p*80 + cc*20;
  int* ie = idxpart + (size_t)p*80 + cc*20;
  #pragma unroll
  for (int i = 0; i < KNN; i++) { pe[i] = pdl[i]; ie[i] = idl[i]; }
}

// ---------- 3) conv1 fused: mobius feature + 64ch conv + stats + max/min over k ----------
__global__ void __launch_bounds__(256) k_conv1(const float* __restrict__ xp1, const int* __restrict__ idx1,
                        const float* __restrict__ w1, float* __restrict__ hmax1,
                        float* __restrict__ hmin1, double* __restrict__ stats1sh) {
  __shared__ float F[4][KNN][6];
  __shared__ float red[4][64][2];
  int g = threadIdx.x >> 6, lane = threadIdx.x & 63;
  float w[6];
  #pragma unroll
  for (int c = 0; c < 6; c++) w[c] = w1[lane*6 + c];
  float sum = 0.f, sumsq = 0.f;
  int pbase = blockIdx.x * 16;
  for (int it = 0; it < 4; ++it) {
    int p = pbase + it*4 + g;
    if (lane < KNN) {
      int nb = idx1[p*KNN + lane];
      int bb = p >> 10;
      const float* xc = xp1 + p*3;
      const float* ft = xp1 + (bb*N_ + nb)*3;
      float x0 = ft[0], x1 = ft[1], x2v = ft[2];
      float c0 = xc[0], c1 = xc[1], c2 = xc[2];
      float X2 = x0*x0 + x1*x1 + x2v*x2v;
      float Y2 = c0*c0 + c1*c1 + c2*c2;
      float XY = -(x0*c0 + x1*c1 + x2v*c2);
      float den = fmaxf(1.0f + 0.02f*XY + 1e-4f*X2*Y2, 1e-15f);
      float s1 = (1.0f + 0.02f*XY + 0.01f*Y2) / den;
      float s2 = (1.0f - 0.01f*X2) / den;
      F[g][lane][0] = s1*x0 - s2*c0;
      F[g][lane][1] = s1*x1 - s2*c1;
      F[g][lane][2] = s1*x2v - s2*c2;
      F[g][lane][3] = c0; F[g][lane][4] = c1; F[g][lane][5] = c2;
    }
    __syncthreads();
    float mx = -__builtin_inff(), mn = __builtin_inff();
    for (int k = 0; k < KNN; k++) {
      float h = 0.f;
      #pragma unroll
      for (int c = 0; c < 6; c++) h = fmaf(w[c], F[g][k][c], h);
      mx = fmaxf(mx, h); mn = fminf(mn, h);
      sum += h; sumsq += h*h;
    }
    hmax1[p*64 + lane] = mx;
    hmin1[p*64 + lane] = mn;
    __syncthreads();
  }
  red[g][lane][0] = sum; red[g][lane][1] = sumsq;
  __syncthreads();
  if (g == 0) {
    float s  = red[0][lane][0] + red[1][lane][0] + red[2][lane][0] + red[3][lane][0];
    float s2 = red[0][lane][1] + red[1][lane][1] + red[2][lane][1] + red[3][lane][1];
    double* dst = stats1sh + ((size_t)(blockIdx.x & 63)*64 + lane)*2;
    atomicAdd(dst, (double)s);
    atomicAdd(dst + 1, (double)s2);
  }
}

// ---------- BN stat reduce (shadows -> scale/shift) ----------
__global__ void k_bn_reduce(const double* __restrict__ sh, int nsh, int nch, double cnt,
                            const float* __restrict__ g, const float* __restrict__ bb,
                            float* __restrict__ scale, float* __restrict__ shift) {
  int o = blockIdx.x * blockDim.x + threadIdx.x;
  if (o >= nch) return;
  double s = 0.0, s2 = 0.0;
  for (int i = 0; i < nsh; i++) {
    s  += sh[((size_t)i*nch + o)*2];
    s2 += sh[((size_t)i*nch + o)*2 + 1];
  }
  double m = s / cnt;
  double v = s2 / cnt - m*m;
  float a = g[o] / sqrtf((float)v + 1e-5f);
  scale[o] = a;
  shift[o] = bb[o] - a * (float)m;
}

// ---------- 5) BN1 apply + relu (+max already folded) + e2p of x1 ----------
__global__ void __launch_bounds__(256) k_bn1_apply(const float* __restrict__ hmax1, const float* __restrict__ hmin1,
                            const float* __restrict__ scale1, const float* __restrict__ shift1,
                            float* __restrict__ feat3, float* __restrict__ xp2) {
  int p = blockIdx.x*4 + (threadIdx.x >> 6);
  int c = threadIdx.x & 63;
  float a = scale1[c], t = shift1[c];
  float h = (a >= 0.f) ? hmax1[p*64 + c] : hmin1[p*64 + c];
  float x1 = fmaxf(fmaf(a, h, t), 0.f);
  feat3[p*256 + c] = x1;
  float n2 = x1*x1;
  #pragma unroll
  for (int off = 32; off > 0; off >>= 1) n2 += __shfl_xor(n2, off);
  float n = fmaxf(sqrtf(n2), 1e-15f);
  float th = tanhf(0.1f * n);
  float sc = th / (0.1f * n);
  float ny = fmaxf(th * 10.0f, 1e-15f);
  float mxn = (1.0f - 4e-3f) / 0.1f;
  if (ny > mxn) sc *= mxn / ny;
  xp2[p*64 + c] = sc * x1;
}

// ---------- 6) knn on 64-d x1 (4-way candidate split) ----------
__global__ void __launch_bounds__(128) k_knn2(const float* __restrict__ feat3,
        float* __restrict__ pdpart, int* __restrict__ idxpart) {
  __shared__ float Ct[128][64];
  __shared__ float XXs[128];
  int blk = blockIdx.x;
  int b = blk >> 5, rc = (blk >> 2) & 7, cc = blk & 3;
  int row = rc*128 + threadIdx.x;
  int p = b*N_ + row;
  float4 q[16];
  const float4* qv = (const float4*)(feat3 + (size_t)p*256);
  #pragma unroll
  for (int i = 0; i < 16; i++) q[i] = qv[i];
  float xxq = 0.f;
  #pragma unroll
  for (int i = 0; i < 16; i++) xxq += q[i].x*q[i].x + q[i].y*q[i].y + q[i].z*q[i].z + q[i].w*q[i].w;
  float pdl[KNN]; int idl[KNN];
  #pragma unroll
  for (int i = 0; i < KNN; i++) { pdl[i] = -__builtin_inff(); idl[i] = 0; }
  for (int sub = 0; sub < 2; ++sub) {
    int cbase = cc*256 + sub*128;
    __syncthreads();
    for (int e = threadIdx.x; e < 128*16; e += 128) {
      int rr = e >> 4, c4 = e & 15;
      ((float4*)Ct[rr])[c4] = *((const float4*)(feat3 + (size_t)(b*N_ + cbase + rr)*256) + c4);
    }
    __syncthreads();
    {
      float s = 0.f;
      const float4* cr = (const float4*)Ct[threadIdx.x];
      #pragma unroll
      for (int i = 0; i < 16; i++) { float4 v = cr[i]; s += v.x*v.x + v.y*v.y + v.z*v.z + v.w*v.w; }
      XXs[threadIdx.x] = s;
    }
    __syncthreads();
    for (int j = 0; j < 128; j++) {
      const float4* cj = (const float4*)Ct[j];
      float dot = 0.f;
      #pragma unroll
      for (int i = 0; i < 16; i++) {
        float4 v = cj[i];
        dot = fmaf(q[i].x, v.x, dot); dot = fmaf(q[i].y, v.y, dot);
        dot = fmaf(q[i].z, v.z, dot); dot = fmaf(q[i].w, v.w, dot);
      }
      float d = 2.0f*dot - xxq - XXs[j];
      if (d > pdl[KNN-1]) topk_insert(pdl, idl, d, cbase + j);
    }
  }
  float* pe = pdpart + (size_t)p*80 + cc*20;
  int* ie = idxpart + (size_t)p*80 + cc*20;
  #pragma unroll
  for (int i = 0; i < KNN; i++) { pe[i] = pdl[i]; ie[i] = idl[i]; }
}

// ---------- 7) merge 4 sorted top-20 chunks ----------
__global__ void k_knn2_merge(const float* __restrict__ pdpart, const int* __restrict__ idxpart,
                             int* __restrict__ idx2) {
  int p = blockIdx.x*256 + threadIdx.x;
  if (p >= NPAIR) return;
  const float* pe = pdpart + (size_t)p*80;
  const int* ie = idxpart + (size_t)p*80;
  int pos0 = 0, pos1 = 0, pos2 = 0, pos3 = 0;
  int* outp = idx2 + p*KNN;
  for (int t = 0; t < KNN; t++) {
    float best = -__builtin_inff(); int bi = 0x7FFFFFFF; int bc = 0;
    if (pos0 < KNN) { float pv = pe[pos0];      int iv = ie[pos0];      if (pv > best || (pv == best && iv < bi)) { best = pv; bi = iv; bc = 0; } }
    if (pos1 < KNN) { float pv = pe[20 + pos1]; int iv = ie[20 + pos1]; if (pv > best || (pv == best && iv < bi)) { best = pv; bi = iv; bc = 1; } }
    if (pos2 < KNN) { float pv = pe[40 + pos2]; int iv = ie[40 + pos2]; if (pv > best || (pv == best && iv < bi)) { best = pv; bi = iv; bc = 2; } }
    if (pos3 < KNN) { float pv = pe[60 + pos3]; int iv = ie[60 + pos3]; if (pv > best || (pv == best && iv < bi)) { best = pv; bi = iv; bc = 3; } }
    outp[t] = bi;
    if (bc == 0) pos0++; else if (bc == 1) pos1++; else if (bc == 2) pos2++; else pos3++;
  }
}

// ---------- 8) weight transposes ----------
__global__ void k_transpose(const float* __restrict__ w2, const float* __restrict__ w3,
                            float* __restrict__ wt2, float* __restrict__ wt3) {
  int i = blockIdx.x*256 + threadIdx.x;
  if (i < 192*128) { int o = i/128, c = i%128; wt2[c*192 + o] = w2[i]; }
  if (i < 1024*256) { int o = i/256, c = i%256; wt3[c*1024 + o] = w3[i]; }
}

// ---------- 9) conv2 fused: on-the-fly mobius A-tile + GEMM + stats + max/min over k ----------
__global__ void __launch_bounds__(256) k_conv2(const float* __restrict__ xp2,
    const int* __restrict__ idx2, const float* __restrict__ wt2,
    float* __restrict__ hmax2, float* __restrict__ hmin2, double* __restrict__ stats2sh) {
  __shared__ __align__(16) float A[80*132];
  __shared__ __align__(16) float xcs[256];
  __shared__ float s1s[80], s2s[80];
  __shared__ int nbr[80];
  int tid = threadIdx.x;
  int ty = tid >> 4, tx = tid & 15;
  int p0 = blockIdx.x * 4;
  int b = p0 >> 10;
  {
    int g = tid >> 6, c = tid & 63;
    xcs[tid] = xp2[(size_t)(p0 + g)*64 + c];
  }
  if (tid < 80) nbr[tid] = idx2[p0*KNN + tid];
  __syncthreads();
  // phase1: A[r][0:64] = neighbor feat, A[r][64:128] = xc
  for (int e = tid; e < 80*32; e += 256) {
    int r = e >> 5, qq = e & 31;
    if (qq < 16) {
      float4 v = *((const float4*)(xp2 + (size_t)(b*N_ + nbr[r])*64) + qq);
      *((float4*)(A + r*132) + qq) = v;
    } else {
      int g = r / 20;
      *((float4*)(A + r*132 + 64) + (qq - 16)) = *((const float4*)(xcs + g*64) + (qq - 16));
    }
  }
  __syncthreads();
  // phase2: per-row mobius scalars
  if (tid < 80) {
    const float* Ar = A + tid*132;
    float X2 = 0.f, XY = 0.f, Y2 = 0.f;
    for (int c2 = 0; c2 < 64; c2++) {
      float f = Ar[c2], xcv = Ar[64 + c2];
      X2 = fmaf(f, f, X2); XY = fmaf(-f, xcv, XY); Y2 = fmaf(xcv, xcv, Y2);
    }
    float den = fmaxf(1.0f + 0.02f*XY + 1e-4f*X2*Y2, 1e-15f);
    s1s[tid] = (1.0f + 0.02f*XY + 0.01f*Y2) / den;
    s2s[tid] = (1.0f - 0.01f*X2) / den;
  }
  __syncthreads();
  // phase3: A[r][0:64] = s1*feat - s2*xc
  for (int e = tid; e < 80*16; e += 256) {
    int r = e >> 4, qq = e & 15;
    float4 f = *((float4*)(A + r*132) + qq);
    float4 c4v = *((const float4*)(A + r*132 + 64) + qq);
    float s1 = s1s[r], s2 = s2s[r];
    f.x = s1*f.x - s2*c4v.x; f.y = s1*f.y - s2*c4v.y;
    f.z = s1*f.z - s2*c4v.z; f.w = s1*f.w - s2*c4v.w;
    *((float4*)(A + r*132) + qq) = f;
  }
  __syncthreads();
  // GEMM: 80x192, K=128
  float acc[5][12];
  #pragma unroll
  for (int i = 0; i < 5; i++)
    #pragma unroll
    for (int j = 0; j < 12; j++) acc[i][j] = 0.f;
  const float4* wtv = (const float4*)wt2;
  for (int kc = 0; kc < 128; kc++) {
    float4 w0 = wtv[kc*48 + tx];
    float4 w1 = wtv[kc*48 + 16 + tx];
    float4 w2 = wtv[kc*48 + 32 + tx];
    float wv[12] = {w0.x,w0.y,w0.z,w0.w, w1.x,w1.y,w1.z,w1.w, w2.x,w2.y,w2.z,w2.w};
    float ar[5];
    #pragma unroll
    for (int i = 0; i < 5; i++) ar[i] = A[(ty + 16*i)*132 + kc];
    #pragma unroll
    for (int i = 0; i < 5; i++) {
      #pragma unroll
      for (int j = 0; j < 12; j++) acc[i][j] = fmaf(ar[i], wv[j], acc[i][j]);
    }
  }
  __syncthreads();
  // stats: per-channel sum/sumsq -> shadow atomics
  float* redbuf = A;   // reuse (needs 256*25 = 6400 floats)
  #pragma unroll
  for (int cc2 = 0; cc2 < 12; cc2++) {
    float s = 0.f, s2 = 0.f;
    #pragma unroll
    for (int i = 0; i < 5; i++) { float h = acc[i][cc2]; s += h; s2 += h*h; }
    redbuf[tid*25 + cc2*2] = s; redbuf[tid*25 + cc2*2 + 1] = s2;
  }
  __syncthreads();
  if (ty == 0) {
    for (int cc2 = 0; cc2 < 12; cc2++) {
      float s = 0.f, s2 = 0.f;
      for (int yy = 0; yy < 16; yy++) {
        s  += redbuf[(yy*16 + tx)*25 + cc2*2];
        s2 += redbuf[(yy*16 + tx)*25 + cc2*2 + 1];
      }
      int o = (cc2 >> 2)*64 + 4*tx + (cc2 & 3);
      double* dst = stats2sh + ((size_t)(blockIdx.x & 63)*192 + o)*2;
      atomicAdd(dst, (double)s); atomicAdd(dst + 1, (double)s2);
    }
  }
  // max/min over k per (pair, channel)
  float* mmb = A;
  #pragma unroll
  for (int cc2 = 0; cc2 < 12; cc2++) {
    __syncthreads();
    #pragma unroll
    for (int i = 0; i < 5; i++) mmb[(ty + 16*i)*16 + tx] = acc[i][cc2];
    __syncthreads();
    if (tid < 64) {
      int g = tid >> 4, xx2 = tid & 15;
      float mx = -__builtin_inff(), mn = __builtin_inff();
      for (int kk = 0; kk < KNN; kk++) {
        float h = mmb[(g*20 + kk)*16 + xx2];
        mx = fmaxf(mx, h); mn = fminf(mn, h);
      }
      int o = (cc2 >> 2)*64 + 4*xx2 + (cc2 & 3);
      hmax2[(size_t)(p0 + g)*192 + o] = mx;
      hmin2[(size_t)(p0 + g)*192 + o] = mn;
    }
  }
}

// ---------- 10) BN2 apply ----------
__global__ void k_bn2_apply(const float* __restrict__ hmax2, const float* __restrict__ hmin2,
                            const float* __restrict__ scale2, const float* __restrict__ shift2,
                            float* __restrict__ feat3) {
  int e = blockIdx.x*256 + threadIdx.x;
  if (e >= NPAIR*192) return;
  int p = e / 192, o = e - p*192;
  float a = scale2[o], t = shift2[o];
  float h = (a >= 0.f) ? hmax2[e] : hmin2[e];
  feat3[(size_t)p*256 + 64 + o] = fmaxf(fmaf(a, h, t), 0.f);
}

// ---------- 11) conv3 GEMM + stats + max/min over n ----------
__global__ void __launch_bounds__(256) k_conv3(const float* __restrict__ feat3,
   const float* __restrict__ wt3, double* __restrict__ stats3,
   unsigned* __restrict__ hmax3u, unsigned* __restrict__ hmin3u) {
  __shared__ __align__(16) float A[64*68];
  __shared__ float buf[256*16];
  int tid = threadIdx.x, ty = tid >> 4, tx = tid & 15;
  int mt = blockIdx.x >> 2, cb = blockIdx.x & 3;
  int rowbase = mt*64;
  int b = rowbase >> 10;
  float acc[4][16];
  #pragma unroll
  for (int i = 0; i < 4; i++)
    #pragma unroll
    for (int j = 0; j < 16; j++) acc[i][j] = 0.f;
  for (int ch = 0; ch < 4; ch++) {
    int kb = ch*64;
    __syncthreads();
    for (int e = tid; e < 64*16; e += 256) {
      int rr = e >> 4, c4 = e & 15;
      *((float4*)(A + rr*68) + c4) = *((const float4*)(feat3 + (size_t)(rowbase + rr)*256 + kb) + c4);
    }
    __syncthreads();
    for (int kc = 0; kc < 64; kc++) {
      int kglob = kb + kc;
      float4 w[4];
      #pragma unroll
      for (int j = 0; j < 4; j++)
        w[j] = *((const float4*)(wt3 + (size_t)kglob*1024 + cb*256 + j*64 + 4*tx));
      float a[4];
      #pragma unroll
      for (int i = 0; i < 4; i++) a[i] = A[(ty + 16*i)*68 + kc];
      #pragma unroll
      for (int i = 0; i < 4; i++) {
        #pragma unroll
        for (int j = 0; j < 4; j++) {
          acc[i][j*4+0] = fmaf(a[i], w[j].x, acc[i][j*4+0]);
          acc[i][j*4+1] = fmaf(a[i], w[j].y, acc[i][j*4+1]);
          acc[i][j*4+2] = fmaf(a[i], w[j].z, acc[i][j*4+2]);
          acc[i][j*4+3] = fmaf(a[i], w[j].w, acc[i][j*4+3]);
        }
      }
    }
  }
  #pragma unroll
  for (int j = 0; j < 4; j++) {
    __syncthreads();
    #pragma unroll
    for (int q = 0; q < 4; q++) {
      float s = 0.f, s2 = 0.f, mx = -__builtin_inff(), mn = __builtin_inff();
      #pragma unroll
      for (int i = 0; i < 4; i++) {
        float h = acc[i][j*4+q];
        s += h; s2 += h*h; mx = fmaxf(mx, h); mn = fminf(mn, h);
      }
      float* bp = buf + tid*16 + q*4;
      bp[0] = s; bp[1] = s2; bp[2] = mx; bp[3] = mn;
    }
    __syncthreads();
    if (ty == 0) {
      #pragma unroll
      for (int q = 0; q < 4; q++) {
        float s = 0.f, s2 = 0.f, mx = -__builtin_inff(), mn = __builtin_inff();
        for (int yy = 0; yy < 16; yy++) {
          const float* bp = buf + (yy*16 + tx)*16 + q*4;
          s += bp[0]; s2 += bp[1]; mx = fmaxf(mx, bp[2]); mn = fminf(mn, bp[3]);
        }
        int o = cb*256 + j*64 + 4*tx + q;
        atomicAdd(stats3 + (size_t)o*2, (double)s);
        atomicAdd(stats3 + (size_t)o*2 + 1, (double)s2);
        atomicMax(hmax3u + b*1024 + o, fkey(mx));
        atomicMin(hmin3u + b*1024 + o, fkey(mn));
      }
    }
  }
}

// ---------- 12) head ----------
__device__ float blk_reduce(float v, float* red, int tid) {
  red[tid] = v; __syncthreads();
  for (int st = 128; st > 0; st >>= 1) {
    if (tid < st) red[tid] += red[tid + st];
    __syncthreads();
  }
  float r = red[0]; __syncthreads();
  return r;
}

__global__ void __launch_bounds__(256) k_head(const unsigned* __restrict__ hmax3u, const unsigned* __restrict__ hmin3u,
    const float* __restrict__ scale3, const float* __restrict__ shift3,
    const float* __restrict__ fc1w, const float* __restrict__ fc1b,
    const float* __restrict__ ln1g, const float* __restrict__ ln1b,
    const float* __restrict__ fc2w, const float* __restrict__ fc2b,
    const float* __restrict__ ln2g, const float* __restrict__ ln2b,
    const float* __restrict__ outw, const float* __restrict__ outb,
    float* __restrict__ out) {
  __shared__ __align__(16) float V[1024];
  __shared__ __align__(16) float H1[512];
  __shared__ __align__(16) float H2[256];
  __shared__ float red[256];
  int b = blockIdx.x, tid = threadIdx.x;
  for (int o = tid; o < 1024; o += 256) {
    float a = scale3[o];
    unsigned u = (a >= 0.f) ? hmax3u[b*1024 + o] : hmin3u[b*1024 + o];
    float h = fkeyinv(u);
    V[o] = fmaxf(fmaf(a, h, shift3[o]), 0.f);
  }
  __syncthreads();
  float h1v[2];
  #pragma unroll
  for (int ii = 0; ii < 2; ii++) {
    int o = tid + ii*256;
    const float4* wr = (const float4*)(fc1w + (size_t)o*1024);
    float s = 0.f;
    for (int c4 = 0; c4 < 256; c4++) {
      float4 w = wr[c4]; float4 vv = ((const float4*)V)[c4];
      s = fmaf(w.x, vv.x, s); s = fmaf(w.y, vv.y, s);
      s = fmaf(w.z, vv.z, s); s = fmaf(w.w, vv.w, s);
    }
    h1v[ii] = s + fc1b[o];
  }
  float s = h1v[0] + h1v[1];
  float s2 = h1v[0]*h1v[0] + h1v[1]*h1v[1];
  s = blk_reduce(s, red, tid);
  s2 = blk_reduce(s2, red, tid);
  float m = s / 512.f;
  float var = s2 / 512.f - m*m;
  float inv = 1.0f / sqrtf(var + 1e-5f);
  #pragma unroll
  for (int ii = 0; ii < 2; ii++) {
    int o = tid + ii*256;
    H1[o] = fmaxf((h1v[ii] - m)*inv*ln1g[o] + ln1b[o], 0.f);
  }
  __syncthreads();
  float h2v;
  {
    const float4* wr = (const float4*)(fc2w + (size_t)tid*512);
    float t = 0.f;
    for (int c4 = 0; c4 < 128; c4++) {
      float4 w = wr[c4]; float4 vv = ((const float4*)H1)[c4];
      t = fmaf(w.x, vv.x, t); t = fmaf(w.y, vv.y, t);
      t = fmaf(w.z, vv.z, t); t = fmaf(w.w, vv.w, t);
    }
    h2v = t + fc2b[tid];
  }
  float ss = blk_reduce(h2v, red, tid);
  float ss2 = blk_reduce(h2v*h2v, red, tid);
  float m2 = ss / 256.f;
  float var2 = ss2 / 256.f - m2*m2;
  float inv2 = 1.0f / sqrtf(var2 + 1e-5f);
  H2[tid] = fmaxf((h2v - m2)*inv2*ln2g[tid] + ln2b[tid], 0.f);
  __syncthreads();
  if (tid < 40) {
    const float4* wr = (const float4*)(outw + (size_t)tid*256);
    float t = 0.f;
    for (int c4 = 0; c4 < 64; c4++) {
      float4 w = wr[c4]; float4 vv = ((const float4*)H2)[c4];
      t = fmaf(w.x, vv.x, t); t = fmaf(w.y, vv.y, t);
      t = fmaf(w.z, vv.z, t); t = fmaf(w.w, vv.w, t);
    }
    red[tid] = t + outb[tid];
  }
  __syncthreads();
  if (tid == 0) {
    float mx = -__builtin_inff();
    for (int i2 = 0; i2 < 40; i2++) mx = fmaxf(mx, red[i2]);
    float se = 0.f;
    for (int i2 = 0; i2 < 40; i2++) se += expf(red[i2] - mx);
    float lse = mx + logf(se);
    for (int i2 = 0; i2 < 40; i2++) out[b*40 + i2] = red[i2] - lse;
  }
}

extern "C" void kernel_launch(void* const* d_in, const int* in_sizes, int n_in,
                              void* d_out, int out_size, void* d_ws, size_t ws_size,
                              hipStream_t stream) {
  (void)in_sizes; (void)n_in; (void)out_size; (void)ws_size;
  const float* x    = (const float*)d_in[0];
  const float* w1   = (const float*)d_in[1];
  const float* bn1g = (const float*)d_in[2];
  const float* bn1b = (const float*)d_in[3];
  const float* w2   = (const float*)d_in[4];
  const float* bn2g = (const float*)d_in[5];
  const float* bn2b = (const float*)d_in[6];
  const float* w3   = (const float*)d_in[7];
  const float* bn3g = (const float*)d_in[8];
  const float* bn3b = (const float*)d_in[9];
  const float* fc1w = (const float*)d_in[10];
  const float* fc1b = (const float*)d_in[11];
  const float* ln1g = (const float*)d_in[12];
  const float* ln1b = (const float*)d_in[13];
  const float* fc2w = (const float*)d_in[14];
  const float* fc2b = (const float*)d_in[15];
  const float* ln2g = (const float*)d_in[16];
  const float* ln2b = (const float*)d_in[17];
  const float* outw = (const float*)d_in[18];
  const float* outb = (const float*)d_in[19];
  float* out = (float*)d_out;

  float* ws = (float*)d_ws;
  size_t off = 0;
  float* xp1   = ws + off; off += 49152;
  int*   idx1  = (int*)(ws + off); off += 327680;
  float* hmax1 = ws + off; off += 1048576;
  float* hmin1 = ws + off; off += 1048576;
  float* feat3 = ws + off; off += 4194304;
  float* xp2   = ws + off; off += 1048576;
  float* hmax2 = ws + off; off += 3145728;   // also pdpart (knn1 + knn2 partials)
  float* hmin2 = ws + off; off += 3145728;   // also idxpart
  int*   idx2  = (int*)(ws + off); off += 327680;
  float* wt2   = ws + off; off += 24576;
  float* wt3   = ws + off; off += 262144;
  float* scale1 = ws + off; off += 64;
  float* shift1 = ws + off; off += 64;
  float* scale2 = ws + off; off += 192;
  float* shift2 = ws + off; off += 192;
  float* scale3 = ws + off; off += 1024;
  float* shift3 = ws + off; off += 1024;
  double* stats1sh = (double*)(ws + off);      // 64*64*2 doubles
  double* stats2sh = stats1sh + 64*64*2;       // 64*192*2 doubles
  double* stats3   = stats2sh + 64*192*2;      // 1024*2 doubles
  unsigned* hmax3u = (unsigned*)(stats3 + 1024*2);  // 16384 u32
  unsigned* hmin3u = hmax3u + 16384;                // 16384 u32
  float* pdpart = hmax2;
  int*   idxpart = (int*)hmin2;

  size_t zero_bytes = (size_t)(64*64*2 + 64*192*2 + 1024*2)*8 + (size_t)16384*4;
  hipMemsetAsync(stats1sh, 0, zero_bytes, stream);
  hipMemsetAsync(hmin3u, 0xFF, (size_t)16384*4, stream);

  k_e2p1<<<64, 256, 0, stream>>>(x, xp1);
  k_knn1_part<<<256, 256, 0, stream>>>(x, pdpart, idxpart);
  k_knn2_merge<<<64, 256, 0, stream>>>(pdpart, idxpart, idx1);
  k_transpose<<<1024, 256, 0, stream>>>(w2, w3, wt2, wt3);
  k_conv1<<<1024, 256, 0, stream>>>(xp1, idx1, w1, hmax1, hmin1, stats1sh);
  k_bn_reduce<<<1, 64, 0, stream>>>(stats1sh, 64, 64, 327680.0, bn1g, bn1b, scale1, shift1);
  k_bn1_apply<<<4096, 256, 0, stream>>>(hmax1, hmin1, scale1, shift1, feat3, xp2);
  k_knn2<<<512, 128, 0, stream>>>(feat3, pdpart, idxpart);
  k_knn2_merge<<<64, 256, 0, stream>>>(pdpart, idxpart, idx2);
  k_conv2<<<4096, 256, 0, stream>>>(xp2, idx2, wt2, hmax2, hmin2, stats2sh);
  k_bn_reduce<<<1, 192, 0, stream>>>(stats2sh, 64, 192, 327680.0, bn2g, bn2b, scale2, shift2);
  k_bn2_apply<<<12288, 256, 0, stream>>>(hmax2, hmin2, scale2, shift2, feat3);
  k_conv3<<<1024, 256, 0, stream>>>(feat3, wt3, stats3, hmax3u, hmin3u);
  k_bn_reduce<<<4, 256, 0, stream>>>(stats3, 1, 1024, 16384.0, bn3g, bn3b, scale3, shift3);
  k_head<<<16, 256, 0, stream>>>(hmax3u, hmin3u, scale3, shift3,
                                 fc1w, fc1b, ln1g, ln1b,
                                 fc2w, fc2b, ln2g, ln2b,
                                 outw, outb, out);
}